// Round 3
// baseline (243.601 us; speedup 1.0000x reference)
//
#include <hip/hip_runtime.h>
#include <hip/hip_bf16.h>

// MinGRU forward: z=sigmoid(xWz^T), h~=xWh^T, a=1-z+1e-8, b=z*h~, scan h=a*h+b.
// B=4 T=4096 D=1024.
// R6: GEMM restructured to the 8-phase-style counted-vmcnt schedule (T3+T4+T5).
// Key enabler: Wz/Wh interleaved into W_cat (2048x1024) in 16-row groups, so a
// SINGLE-accumulator 256x256-tile GEMM (acc=128 VGPR/wave, feasible) computes
// both pre-activations, and fragment pair (j=2u, 2u+1) holds (pz, ph) for the
// SAME d on the SAME lanes -> fused gate epilogue unchanged in structure.
// Schedule: BK=32, 16 iterations x 4 phases; per phase {ds_read frags | 2
// global_load_lds stage | s_barrier | setprio(1) 16 MFMA setprio(0) |
// s_barrier}; vmcnt(4) twice per iteration (counted, never drained to 0 except
// the peeled last iteration). LDS 128KB = 2-iteration double buffer. LDS layout
// is the pre-tiled fragment layout (conflict-free; T2 swizzle unnecessary,
// SQ_LDS_BANK_CONFLICT measured 0). XCD-chunked block swizzle (512%8==0).
// pass2 (R5 coalesced serial scan) and pass3 unchanged.

typedef __bf16 bf16x8 __attribute__((ext_vector_type(8)));
typedef __bf16 bf16x4 __attribute__((ext_vector_type(4)));
typedef float  f32x4  __attribute__((ext_vector_type(4)));

#define BSZ 4
#define TSZ 4096
#define DSZ 1024
#define MSZ (BSZ*TSZ)      // 16384 rows
#define NSZ 2048           // concat-N (z|h interleaved by 16-col groups)
#define CH  16             // scan chunk length
#define NC  (TSZ/CH)       // 256 chunks per sequence

#define BAR()  asm volatile("s_barrier" ::: "memory")
#define VMW(n) asm volatile("s_waitcnt vmcnt(" #n ")" ::: "memory")

__device__ __forceinline__ void gload_lds16(const __bf16* g, __bf16* l) {
  __builtin_amdgcn_global_load_lds(
      (const __attribute__((address_space(1))) void*)g,
      (__attribute__((address_space(3))) void*)l, 16, 0, 0);
}

// ---------------- conversion: fp32 row-major -> bf16 fragment-tiled ----------------
// tiled layout per 128-row block: [kblk:32][i:8][l:64][j:8] where
//   row = i*16 + (l&15), k = kblk*32 + (l>>4)*8 + j
// W_cat row g*16+s: g even -> Wz row (g>>1)*16+s, g odd -> Wh row (g>>1)*16+s.
__global__ void convert_tile_kernel(const float* __restrict__ X,
                                    const float* __restrict__ Wz,
                                    const float* __restrict__ Wh,
                                    __bf16* __restrict__ Xc,
                                    __bf16* __restrict__ Wc)
{
  const int bx = blockIdx.x;
  const float* src; __bf16* dst; int gid; int row;
  if (bx < 8192) {
    gid = bx*256 + threadIdx.x;
    const int l = gid & 63, i = (gid >> 6) & 7, rblk = gid >> 14;
    row = rblk*128 + i*16 + (l & 15);
    src = X; dst = Xc;
  } else {
    gid = (bx - 8192)*256 + threadIdx.x;     // over 2048x1024/8 elems
    const int l = gid & 63, i = (gid >> 6) & 7, rblk = gid >> 14;  // rblk 0..15
    const int g = rblk*8 + i;                // 16-row group of W_cat, 0..127
    row = (g >> 1)*16 + (l & 15);
    src = (g & 1) ? Wh : Wz; dst = Wc;
  }
  const int l    = gid & 63;
  const int kblk = (gid >> 9) & 31;
  const int col  = kblk*32 + (l >> 4)*8;
  const float* g = src + (size_t)row*DSZ + col;
  float4 v0 = *(const float4*)g;
  float4 v1 = *(const float4*)(g + 4);
  bf16x8 p;
  p[0]=(__bf16)v0.x; p[1]=(__bf16)v0.y; p[2]=(__bf16)v0.z; p[3]=(__bf16)v0.w;
  p[4]=(__bf16)v1.x; p[5]=(__bf16)v1.y; p[6]=(__bf16)v1.z; p[7]=(__bf16)v1.w;
  *(bf16x8*)(dst + (size_t)gid*8) = p;
}

// ---------------- GEMM (256x256 tile, 4-phase counted-vmcnt) + gate epilogue ----
// 512 threads = 8 waves (2M x 4N), per-wave 128x64 output, acc[8][4] f32x4.
// K = 1024 = 16 iterations x 2 kblks (BK=32 each).
// Iteration t computes kblks {2t,2t+1} from buf[t&1], stages {2t+2,2t+3} into
// buf[~t&1]: P1 stages A(2t+2), P2 B(2t+2) + vmcnt(4), P3 A(2t+3),
// P4 B(2t+3) + vmcnt(4). Counted-wait proof: at each vmcnt(4), outstanding=8
// per wave; newest 4 = this iteration's stages, oldest 4 = exactly the kblk
// the next phase's ds_reads need. Barrier after each vmcnt makes it collective.
__global__ __launch_bounds__(512, 2) void gemm_gate_kernel(
    const __bf16* __restrict__ Xc, const __bf16* __restrict__ Wc,
    const float* __restrict__ bz, const float* __restrict__ bh,
    __bf16* __restrict__ a_ws, float* __restrict__ b_out,
    float* __restrict__ Aprod, float* __restrict__ Bcomp)
{
  // [buf:2][kt:2][half:2][4096 elems] each -> 32768 elems = 64KB per matrix
  __shared__ __align__(16) __bf16 As[32768];
  __shared__ __align__(16) __bf16 Bs[32768];

  const int tid  = threadIdx.x;
  const int lane = tid & 63;
  const int w    = tid >> 6;           // 0..7
  const int wr   = w >> 2;             // 0..1 (M half)
  const int wc   = w & 3;              // 0..3 (N quarter)
  const int lr   = lane & 15;
  const int q    = lane >> 4;

  // XCD-chunked swizzle: 512 wgs, xcd=bid&7 owns contiguous chunk of 64.
  const int bid = blockIdx.x;
  const int wg  = (bid & 7)*64 + (bid >> 3);
  const int bx  = wg >> 3;             // 0..63 (M tiles of 256)
  const int by  = wg & 7;              // 0..7  (N tiles of 256)

  // staging addresses
  const int    lgo   = tid * 8;                        // global elem off in 4096-unit
  const int    llo   = (tid >> 6) * 512;               // wave-uniform LDS elem off
  const size_t xbase = (size_t)bx * 262144 + lgo;      // (bx*2+h)*32 kblks * 4096
  const size_t wbase = (size_t)by * 262144 + lgo;
  // ds_read bases
  const int ard   = wr*4096 + lane*8;                  // + kt*8192(buf) + m*512
  const int bbase = (wc >> 1)*4096 + (wc & 1)*2048 + lane*8;  // + j*512

  f32x4 acc[8][4] = {};
  bf16x8 a4[4], b4[4];

  // prologue: stage kblks 0,1 into buf0 (8 loads/thread; first 4 = kblk0)
  #pragma unroll
  for (int h = 0; h < 2; ++h) gload_lds16(Xc + xbase + h*131072 + 0*4096, As + 0*8192 + h*4096 + llo);
  #pragma unroll
  for (int h = 0; h < 2; ++h) gload_lds16(Wc + wbase + h*131072 + 0*4096, Bs + 0*8192 + h*4096 + llo);
  #pragma unroll
  for (int h = 0; h < 2; ++h) gload_lds16(Xc + xbase + h*131072 + 1*4096, As + 1*8192 + h*4096 + llo);
  #pragma unroll
  for (int h = 0; h < 2; ++h) gload_lds16(Wc + wbase + h*131072 + 1*4096, Bs + 1*8192 + h*4096 + llo);
  VMW(4);   // kblk0 (A+B) complete
  BAR();

  for (int t = 0; t < 16; ++t) {
    const int cur = t & 1, nxt = cur ^ 1;
    const int cb0 = (cur*2 + 0)*8192;   // LDS elem base, kt=0
    const int cb1 = (cur*2 + 1)*8192;   // kt=1
    const int nb0 = (nxt*2 + 0)*8192;
    const int nb1 = (nxt*2 + 1)*8192;
    const size_t g0 = (size_t)(2*t + 2) * 4096;   // next A/B kblk offsets
    const size_t g1 = (size_t)(2*t + 3) * 4096;

    // ---- P1: kblk 2t, m0-3 x j0-3 ----
    #pragma unroll
    for (int m = 0; m < 4; ++m) a4[m] = *(const bf16x8*)(As + cb0 + ard + m*512);
    #pragma unroll
    for (int j = 0; j < 4; ++j) b4[j] = *(const bf16x8*)(Bs + cb0 + bbase + j*512);
    if (t < 15) {
      #pragma unroll
      for (int h = 0; h < 2; ++h) gload_lds16(Xc + xbase + h*131072 + g0, As + nb0 + h*4096 + llo);
    }
    BAR();
    __builtin_amdgcn_s_setprio(1);
    #pragma unroll
    for (int j = 0; j < 4; ++j)
      #pragma unroll
      for (int m = 0; m < 4; ++m)
        acc[m][j] = __builtin_amdgcn_mfma_f32_16x16x32_bf16(a4[m], b4[j], acc[m][j], 0, 0, 0);
    __builtin_amdgcn_s_setprio(0);
    BAR();

    // ---- P2: kblk 2t, m4-7 x j0-3 (b4 reused) ----
    #pragma unroll
    for (int m = 0; m < 4; ++m) a4[m] = *(const bf16x8*)(As + cb0 + ard + (4+m)*512);
    if (t < 15) {
      #pragma unroll
      for (int h = 0; h < 2; ++h) gload_lds16(Wc + wbase + h*131072 + g0, Bs + nb0 + h*4096 + llo);
      VMW(4);   // oldest 4 = kblk 2t+1 stages (prev iter P3/P4) -> done
    } else {
      VMW(0);   // no stages this iter; drain so kblk 31 is complete
    }
    BAR();
    __builtin_amdgcn_s_setprio(1);
    #pragma unroll
    for (int j = 0; j < 4; ++j)
      #pragma unroll
      for (int m = 0; m < 4; ++m)
        acc[4+m][j] = __builtin_amdgcn_mfma_f32_16x16x32_bf16(a4[m], b4[j], acc[4+m][j], 0, 0, 0);
    __builtin_amdgcn_s_setprio(0);
    BAR();

    // ---- P3: kblk 2t+1, m0-3 x j0-3 ----
    #pragma unroll
    for (int m = 0; m < 4; ++m) a4[m] = *(const bf16x8*)(As + cb1 + ard + m*512);
    #pragma unroll
    for (int j = 0; j < 4; ++j) b4[j] = *(const bf16x8*)(Bs + cb1 + bbase + j*512);
    if (t < 15) {
      #pragma unroll
      for (int h = 0; h < 2; ++h) gload_lds16(Xc + xbase + h*131072 + g1, As + nb1 + h*4096 + llo);
    }
    BAR();
    __builtin_amdgcn_s_setprio(1);
    #pragma unroll
    for (int j = 0; j < 4; ++j)
      #pragma unroll
      for (int m = 0; m < 4; ++m)
        acc[m][j] = __builtin_amdgcn_mfma_f32_16x16x32_bf16(a4[m], b4[j], acc[m][j], 0, 0, 0);
    __builtin_amdgcn_s_setprio(0);
    BAR();

    // ---- P4: kblk 2t+1, m4-7 x j0-3 ----
    #pragma unroll
    for (int m = 0; m < 4; ++m) a4[m] = *(const bf16x8*)(As + cb1 + ard + (4+m)*512);
    if (t < 15) {
      #pragma unroll
      for (int h = 0; h < 2; ++h) gload_lds16(Wc + wbase + h*131072 + g1, Bs + nb1 + h*4096 + llo);
      VMW(4);   // oldest 4 = kblk 2t+2 stages (this iter P1/P2) -> done for next P1
    }
    BAR();
    __builtin_amdgcn_s_setprio(1);
    #pragma unroll
    for (int j = 0; j < 4; ++j)
      #pragma unroll
      for (int m = 0; m < 4; ++m)
        acc[4+m][j] = __builtin_amdgcn_mfma_f32_16x16x32_bf16(a4[m], b4[j], acc[4+m][j], 0, 0, 0);
    __builtin_amdgcn_s_setprio(0);
    BAR();
  }

  // ---- epilogue: gate + store + fused per-chunk affine composition ----
  // C_cat col = by*256 + wc*64 + j*16 + lr; col-group parity == j parity.
  // Pair (j=2u, 2u+1) = (pz, ph) for d = (by*8 + wc*2 + u)*16 + lr.
  // Rows: bx*256 + wr*128 + m*16 + q*4 + r; CH=16 -> each m-frag is one chunk.
  const int rowb = bx*256 + wr*128;
  #pragma unroll
  for (int u = 0; u < 2; ++u) {
    const int e = (by*8 + wc*2 + u)*16 + lr;
    const float bzv = bz[e];
    const float bhv = bh[e];
    float Aseg[8], Bseg[8];
    #pragma unroll
    for (int m = 0; m < 8; ++m) {
      const int mbase = rowb + m*16 + q*4;
      float A = 1.0f, Bv = 0.0f;
      #pragma unroll
      for (int r = 0; r < 4; ++r) {
        const size_t idx = (size_t)(mbase + r)*DSZ + e;
        const float pz = acc[m][2*u][r]   + bzv;
        const float ph = acc[m][2*u+1][r] + bhv;
        const float ex = __expf(-pz);
        const float z  = 1.0f / (1.0f + ex);
        const __bf16 abf = (__bf16)fmaf(ex, z, 1e-8f);  // (1-z) + 1e-8
        const float  af  = (float)abf;                   // rounded, matches pass3
        const float  bf  = z * ph;
        a_ws[idx]  = abf;
        b_out[idx] = bf;
        Bv = fmaf(af, Bv, bf);
        A *= af;
      }
      Aseg[m] = A; Bseg[m] = Bv;
    }
    // q-lane scan (stride 16): q=3 ends with the full 16-row chunk aggregate.
    #pragma unroll
    for (int m = 0; m < 8; ++m) {
      #pragma unroll
      for (int s = 16; s < 64; s <<= 1) {
        const float Ap = __shfl_up(Aseg[m], s, 64);
        const float Bp = __shfl_up(Bseg[m], s, 64);
        if (lane >= s) { Bseg[m] = fmaf(Aseg[m], Bp, Bseg[m]); Aseg[m] *= Ap; }
      }
    }
    if (q == 3) {
      #pragma unroll
      for (int m = 0; m < 8; ++m) {
        const int bc = (rowb + m*16) >> 4;    // = b*NC + chunk (NC=256)
        Aprod[(size_t)bc*DSZ + e] = Aseg[m];
        Bcomp[(size_t)bc*DSZ + e] = Bseg[m];
      }
    }
  }
}

// ---------------- scan pass 2: lane = d (coalesced), serial over chunks ------
// One wave per (b, 64-d slice): 64 waves. 16-deep register batching; all
// accesses 256B wave-coalesced. Hstart aliases Aprod (reads of a batch issue
// before that batch's stores; disjoint cells per thread) -- no __restrict__.
#define P2B 16
__global__ void scan_pass2_kernel(const float* Aprod,
                                  const float* __restrict__ Bcomp,
                                  float* Hstart)
{
  const int lane = threadIdx.x & 63;
  const int b    = blockIdx.x >> 4;
  const int d    = (blockIdx.x & 15) * 64 + lane;
  const size_t base = (size_t)b * NC * DSZ + d;
  float h = 0.0f;
  for (int c0 = 0; c0 < NC; c0 += P2B) {
    float Ar[P2B], Br[P2B];
    #pragma unroll
    for (int c = 0; c < P2B; ++c) {
      Ar[c] = Aprod[base + (size_t)(c0 + c)*DSZ];
      Br[c] = Bcomp[base + (size_t)(c0 + c)*DSZ];
    }
    #pragma unroll
    for (int c = 0; c < P2B; ++c) {
      Hstart[base + (size_t)(c0 + c)*DSZ] = h;
      h = fmaf(Ar[c], h, Br[c]);
    }
  }
}

// ---------------- scan pass 3: apply within chunk (4 d per thread) -----------
__global__ void scan_pass3_kernel(const __bf16* __restrict__ a_ws,
                                  const float* __restrict__ Hstart,
                                  float* __restrict__ out)
{
  const int bc   = blockIdx.x;               // 0..BSZ*NC-1
  const int d0   = threadIdx.x * 4;
  const size_t base = (size_t)bc * CH * DSZ + d0;
  float4 hv = *(const float4*)(Hstart + (size_t)bc*DSZ + d0);
  float h[4] = {hv.x, hv.y, hv.z, hv.w};
  #pragma unroll
  for (int t = 0; t < CH; ++t) {
    bf16x4 a4 = *(const bf16x4*)(a_ws + base + (size_t)t*DSZ);
    float4 b4 = *(const float4*)(out + base + (size_t)t*DSZ);
    const float bb[4] = {b4.x, b4.y, b4.z, b4.w};
    #pragma unroll
    for (int c = 0; c < 4; ++c)
      h[c] = fmaf((float)a4[c], h[c], bb[c]);
    *(float4*)(out + base + (size_t)t*DSZ) = make_float4(h[0], h[1], h[2], h[3]);
  }
}

extern "C" void kernel_launch(void* const* d_in, const int* in_sizes, int n_in,
                              void* d_out, int out_size, void* d_ws, size_t ws_size,
                              hipStream_t stream)
{
  const float* x  = (const float*)d_in[0];
  const float* Wz = (const float*)d_in[1];
  const float* bz = (const float*)d_in[2];
  const float* Wh = (const float*)d_in[3];
  const float* bh = (const float*)d_in[4];
  float* out = (float*)d_out;

  // ws: Xc (32MB) | Wc (4MB) | a (32MB) | Aprod (4MB) | Bcomp (4MB)
  __bf16* Xc   = (__bf16*)d_ws;
  __bf16* Wc   = Xc + (size_t)MSZ * DSZ;
  __bf16* a_ws = Wc + (size_t)NSZ * DSZ;
  float* Aprod  = (float*)(a_ws + (size_t)MSZ * DSZ);
  float* Bcomp  = Aprod + (size_t)BSZ*NC*DSZ;
  float* Hstart = Aprod;   // alias

  convert_tile_kernel<<<9216, 256, 0, stream>>>(x, Wz, Wh, Xc, Wc);
  gemm_gate_kernel<<<512, 512, 0, stream>>>(Xc, Wc, bz, bh, a_ws, out, Aprod, Bcomp);
  scan_pass2_kernel<<<64, 64, 0, stream>>>(Aprod, Bcomp, Hstart);
  scan_pass3_kernel<<<BSZ*NC, 256, 0, stream>>>(a_ws, Hstart, out);
}